// Round 1
// baseline (135.508 us; speedup 1.0000x reference)
//
#include <hip/hip_runtime.h>

#define NV 5
#define NB 4
#define NJ 15
#define HD 128
#define WD 240
#define CX 80
#define CY 80
#define CZ 20
#define NPTS (CX*CY*CZ)   /* 128000 */
#define JP 16             /* padded joint dim: one 64B cache line */

// ---------------------------------------------------------------------------
// Per-view projection result: 4 corner weights (validity+bounding folded in)
// and clamped corner coordinates.
// ---------------------------------------------------------------------------
struct ViewSample {
    float w[4];     // w00, w10, w01, w11 (already * valid * bounding)
    int   cx0, cx1, cy0, cy1;
    float bnd;      // 0 or 1
};

__device__ __forceinline__ ViewSample project_one_view(
    float gx, float gy, float gz,
    const float* __restrict__ cam_R, const float* __restrict__ cam_T,
    const float* __restrict__ cam_f, const float* __restrict__ cam_c,
    const float* __restrict__ cam_k, const float* __restrict__ cam_p,
    const float* __restrict__ center, const float* __restrict__ scale,
    int cb)
{
    const float* R = cam_R + cb*9;
    const float* T = cam_T + cb*3;
    float fx = cam_f[cb*2+0], fy = cam_f[cb*2+1];
    float ccx = cam_c[cb*2+0], ccy = cam_c[cb*2+1];
    float k0 = cam_k[cb*3+0], k1 = cam_k[cb*3+1], k2 = cam_k[cb*3+2];
    float p0 = cam_p[cb*2+0], p1 = cam_p[cb*2+1];
    float cenx = center[cb*2+0], ceny = center[cb*2+1];
    float scx = scale[cb*2+0],  scy = scale[cb*2+1];

    // project_pose
    float dx = gx - T[0], dy = gy - T[1], dz = gz - T[2];
    float xc = R[0]*dx + R[1]*dy + R[2]*dz;
    float yc = R[3]*dx + R[4]*dy + R[5]*dz;
    float zc = R[6]*dx + R[7]*dy + R[8]*dz;
    float invz = 1.0f / (zc + 1e-5f);
    float ux = xc * invz, uy = yc * invz;
    float r2 = ux*ux + uy*uy;
    float radial = 1.0f + k0*r2 + k1*(r2*r2) + k2*(r2*r2*r2);
    float tn = p0*uy + p1*ux;
    float m  = radial + 2.0f*tn;
    float xd = ux*m + p1*r2;
    float yd = uy*m + p0*r2;
    float pixx = fx*xd + ccx;
    float pixy = fy*yd + ccy;

    // bounding (before clip)
    float whx = 2.0f*cenx, why = 2.0f*ceny;
    float bnd = (pixx >= 0.0f && pixy >= 0.0f && pixx < whx && pixy < why) ? 1.0f : 0.0f;
    float mwh = fmaxf(whx, why);
    pixx = fminf(fmaxf(pixx, -1.0f), mwh);
    pixy = fminf(fmaxf(pixy, -1.0f), mwh);

    // affine transform to heatmap coords, then normalized [-1,1]
    float hsx = 200.0f*scx, hsy = 200.0f*scy;
    float xyx = (pixx * (960.0f/hsx) + 960.0f*(-cenx/hsx + 0.5f)) * 0.25f;
    float xyy = (pixy * (512.0f/hsy) + 512.0f*(-ceny/hsy + 0.5f)) * 0.25f;
    float sgx = (xyx / 239.0f) * 2.0f - 1.0f;
    float sgy = (xyy / 127.0f) * 2.0f - 1.0f;
    sgx = fminf(fmaxf(sgx, -1.1f), 1.1f);
    sgy = fminf(fmaxf(sgy, -1.1f), 1.1f);

    // bilinear sample setup (align_corners=True)
    float pxf = (sgx + 1.0f) * 0.5f * 239.0f;
    float pyf = (sgy + 1.0f) * 0.5f * 127.0f;
    float x0f = floorf(pxf), y0f = floorf(pyf);
    float wx = pxf - x0f, wy = pyf - y0f;
    int x0 = (int)x0f, y0 = (int)y0f;
    int x1 = x0 + 1,   y1 = y0 + 1;
    float vx0 = (x0 >= 0 && x0 < WD) ? 1.0f : 0.0f;
    float vx1 = (x1 >= 0 && x1 < WD) ? 1.0f : 0.0f;
    float vy0 = (y0 >= 0 && y0 < HD) ? 1.0f : 0.0f;
    float vy1 = (y1 >= 0 && y1 < HD) ? 1.0f : 0.0f;

    ViewSample s;
    s.cx0 = min(max(x0, 0), WD-1);
    s.cx1 = min(max(x1, 0), WD-1);
    s.cy0 = min(max(y0, 0), HD-1);
    s.cy1 = min(max(y1, 0), HD-1);
    s.w[0] = (1.0f-wx)*(1.0f-wy) * vx0*vy0 * bnd;
    s.w[1] = wx*(1.0f-wy)        * vx1*vy0 * bnd;
    s.w[2] = (1.0f-wx)*wy        * vx0*vy1 * bnd;
    s.w[3] = wx*wy               * vx1*vy1 * bnd;
    s.bnd = bnd;
    return s;
}

// ---------------------------------------------------------------------------
// Pre-pass: [v][b][j][y][x] -> [v][b][y][x][j_pad16]  (one 64B line per pixel)
// ---------------------------------------------------------------------------
__global__ __launch_bounds__(256) void hm_transpose_kernel(
    const float* __restrict__ hm, float* __restrict__ out)
{
    int idx = blockIdx.x * 256 + threadIdx.x;     // over NV*NB*HD*WD = 614400
    if (idx >= NV*NB*HD*WD) return;
    int x  = idx % WD;
    int y  = (idx / WD) % HD;
    int vb = idx / (WD*HD);
    const float* src = hm + ((size_t)vb*NJ*HD + (size_t)y)*WD + x;
    float v[JP];
    #pragma unroll
    for (int j = 0; j < NJ; ++j) v[j] = src[(size_t)j*HD*WD];   // coalesced per j
    v[15] = 0.0f;
    float4* dst = (float4*)(out + (size_t)idx * JP);            // 64B aligned
    dst[0] = make_float4(v[0],  v[1],  v[2],  v[3]);
    dst[1] = make_float4(v[4],  v[5],  v[6],  v[7]);
    dst[2] = make_float4(v[8],  v[9],  v[10], v[11]);
    dst[3] = make_float4(v[12], v[13], v[14], v[15]);
}

// ---------------------------------------------------------------------------
// Main kernel, transposed-heatmap path: 1 cache line per bilinear corner.
// ---------------------------------------------------------------------------
__global__ __launch_bounds__(256) void project_kernel_T(
    const float* __restrict__ hmT,
    const float* __restrict__ cam_R, const float* __restrict__ cam_T,
    const float* __restrict__ cam_f, const float* __restrict__ cam_c,
    const float* __restrict__ cam_k, const float* __restrict__ cam_p,
    const float* __restrict__ center, const float* __restrict__ scale,
    float* __restrict__ out_cubes, float* __restrict__ out_grids)
{
    const int b  = blockIdx.x / (NPTS/256);                  // wave-uniform
    const int nn = (blockIdx.x % (NPTS/256))*256 + threadIdx.x;

    int iz = nn % CZ;
    int iy = (nn / CZ) % CY;
    int ix = nn / (CZ*CY);
    float gx = (float)((double)ix * (8000.0/79.0) - 4000.0);
    float gy = (float)((double)iy * (8000.0/79.0) - 4500.0);
    float gz = (float)((double)iz * (2000.0/19.0) -  200.0);

    float wts[NV][4];
    int   offs[NV][4];
    float den = 0.0f;

    #pragma unroll
    for (int v = 0; v < NV; ++v) {
        int cb = v*NB + b;
        ViewSample s = project_one_view(gx, gy, gz, cam_R, cam_T, cam_f, cam_c,
                                        cam_k, cam_p, center, scale, cb);
        wts[v][0] = s.w[0]; wts[v][1] = s.w[1];
        wts[v][2] = s.w[2]; wts[v][3] = s.w[3];
        int base = cb * (HD*WD*JP);
        offs[v][0] = base + (s.cy0*WD + s.cx0)*JP;
        offs[v][1] = base + (s.cy0*WD + s.cx1)*JP;
        offs[v][2] = base + (s.cy1*WD + s.cx0)*JP;
        offs[v][3] = base + (s.cy1*WD + s.cx1)*JP;
        den += s.bnd;
    }

    float acc[NJ];
    #pragma unroll
    for (int j = 0; j < NJ; ++j) acc[j] = 0.0f;

    #pragma unroll
    for (int v = 0; v < NV; ++v) {
        #pragma unroll
        for (int c = 0; c < 4; ++c) {
            float w = wts[v][c];
            if (w != 0.0f) {
                const float4* p = (const float4*)(hmT + offs[v][c]);
                float4 q0 = p[0], q1 = p[1], q2 = p[2], q3 = p[3];
                acc[0]  += w*q0.x; acc[1]  += w*q0.y; acc[2]  += w*q0.z; acc[3]  += w*q0.w;
                acc[4]  += w*q1.x; acc[5]  += w*q1.y; acc[6]  += w*q1.z; acc[7]  += w*q1.w;
                acc[8]  += w*q2.x; acc[9]  += w*q2.y; acc[10] += w*q2.z; acc[11] += w*q2.w;
                acc[12] += w*q3.x; acc[13] += w*q3.y; acc[14] += w*q3.z;
            }
        }
    }

    float inv_den = 1.0f / (den + 1e-6f);
    #pragma unroll
    for (int j = 0; j < NJ; ++j) {
        float val = fminf(fmaxf(acc[j]*inv_den, 0.0f), 1.0f);
        out_cubes[((size_t)b*NJ + j)*NPTS + nn] = val;       // coalesced
    }
    float* g = out_grids + ((size_t)b*NPTS + nn)*3;
    g[0] = gx; g[1] = gy; g[2] = gz;
}

// ---------------------------------------------------------------------------
// Fallback: direct gather from the native layout (if ws too small).
// ---------------------------------------------------------------------------
__global__ __launch_bounds__(256) void project_kernel_direct(
    const float* __restrict__ hm,
    const float* __restrict__ cam_R, const float* __restrict__ cam_T,
    const float* __restrict__ cam_f, const float* __restrict__ cam_c,
    const float* __restrict__ cam_k, const float* __restrict__ cam_p,
    const float* __restrict__ center, const float* __restrict__ scale,
    float* __restrict__ out_cubes, float* __restrict__ out_grids)
{
    const int b  = blockIdx.x / (NPTS/256);
    const int nn = (blockIdx.x % (NPTS/256))*256 + threadIdx.x;

    int iz = nn % CZ;
    int iy = (nn / CZ) % CY;
    int ix = nn / (CZ*CY);
    float gx = (float)((double)ix * (8000.0/79.0) - 4000.0);
    float gy = (float)((double)iy * (8000.0/79.0) - 4500.0);
    float gz = (float)((double)iz * (2000.0/19.0) -  200.0);

    float wts[NV][4];
    int   offs[NV][4];
    float bndv[NV];
    float den = 0.0f;

    #pragma unroll
    for (int v = 0; v < NV; ++v) {
        int cb = v*NB + b;
        ViewSample s = project_one_view(gx, gy, gz, cam_R, cam_T, cam_f, cam_c,
                                        cam_k, cam_p, center, scale, cb);
        wts[v][0] = s.w[0]; wts[v][1] = s.w[1];
        wts[v][2] = s.w[2]; wts[v][3] = s.w[3];
        offs[v][0] = s.cy0*WD + s.cx0;
        offs[v][1] = s.cy0*WD + s.cx1;
        offs[v][2] = s.cy1*WD + s.cx0;
        offs[v][3] = s.cy1*WD + s.cx1;
        bndv[v] = s.bnd;
        den += s.bnd;
    }

    float acc[NJ];
    #pragma unroll
    for (int j = 0; j < NJ; ++j) acc[j] = 0.0f;

    #pragma unroll
    for (int v = 0; v < NV; ++v) {
        if (bndv[v] != 0.0f) {
            int cb = v*NB + b;
            #pragma unroll
            for (int j = 0; j < NJ; ++j) {
                const float* base = hm + ((size_t)cb*NJ + j)*(HD*WD);
                acc[j] += wts[v][0]*base[offs[v][0]] + wts[v][1]*base[offs[v][1]]
                        + wts[v][2]*base[offs[v][2]] + wts[v][3]*base[offs[v][3]];
            }
        }
    }

    float inv_den = 1.0f / (den + 1e-6f);
    #pragma unroll
    for (int j = 0; j < NJ; ++j) {
        float val = fminf(fmaxf(acc[j]*inv_den, 0.0f), 1.0f);
        out_cubes[((size_t)b*NJ + j)*NPTS + nn] = val;
    }
    float* g = out_grids + ((size_t)b*NPTS + nn)*3;
    g[0] = gx; g[1] = gy; g[2] = gz;
}

// ---------------------------------------------------------------------------
extern "C" void kernel_launch(void* const* d_in, const int* in_sizes, int n_in,
                              void* d_out, int out_size, void* d_ws, size_t ws_size,
                              hipStream_t stream) {
    const float* hm     = (const float*)d_in[0];
    const float* cam_R  = (const float*)d_in[1];
    const float* cam_T  = (const float*)d_in[2];
    const float* cam_f  = (const float*)d_in[3];
    const float* cam_c  = (const float*)d_in[4];
    const float* cam_k  = (const float*)d_in[5];
    const float* cam_p  = (const float*)d_in[6];
    const float* center = (const float*)d_in[7];
    const float* scale  = (const float*)d_in[8];

    float* out_cubes = (float*)d_out;
    float* out_grids = out_cubes + (size_t)NB*NJ*NPTS;

    size_t need = (size_t)NV*NB*HD*WD*JP*sizeof(float);   // 39.3 MB
    if (ws_size >= need) {
        float* hmT = (float*)d_ws;
        hipLaunchKernelGGL(hm_transpose_kernel,
                           dim3((NV*NB*HD*WD)/256), dim3(256), 0, stream, hm, hmT);
        hipLaunchKernelGGL(project_kernel_T,
                           dim3(NB*NPTS/256), dim3(256), 0, stream,
                           hmT, cam_R, cam_T, cam_f, cam_c, cam_k, cam_p,
                           center, scale, out_cubes, out_grids);
    } else {
        hipLaunchKernelGGL(project_kernel_direct,
                           dim3(NB*NPTS/256), dim3(256), 0, stream,
                           hm, cam_R, cam_T, cam_f, cam_c, cam_k, cam_p,
                           center, scale, out_cubes, out_grids);
    }
}

// Round 3
// 126.738 us; speedup vs baseline: 1.0692x; 1.0692x over previous
//
#include <hip/hip_runtime.h>
#include <hip/hip_fp16.h>

#define NV 5
#define NB 4
#define NJ 15
#define HD 128
#define WD 240
#define CX 80
#define CY 80
#define CZ 20
#define NPTS (CX*CY*CZ)   /* 128000 */
#define JP16 16           /* padded joint dim in halves: 32B per pixel */
#define BLOCKS_PER_B (NPTS/256)   /* 500 */
#define NWG (NB*BLOCKS_PER_B)     /* 2000, divisible by 8 XCDs */

// ---------------------------------------------------------------------------
struct ViewSample {
    float w[4];     // w00, w10, w01, w11 (validity + bounding folded in)
    int   cx0, cx1, cy0, cy1;
    float bnd;
};

__device__ __forceinline__ ViewSample project_one_view(
    float gx, float gy, float gz,
    const float* __restrict__ cam_R, const float* __restrict__ cam_T,
    const float* __restrict__ cam_f, const float* __restrict__ cam_c,
    const float* __restrict__ cam_k, const float* __restrict__ cam_p,
    const float* __restrict__ center, const float* __restrict__ scale,
    int cb)
{
    const float* R = cam_R + cb*9;
    const float* T = cam_T + cb*3;
    float fx = cam_f[cb*2+0], fy = cam_f[cb*2+1];
    float ccx = cam_c[cb*2+0], ccy = cam_c[cb*2+1];
    float k0 = cam_k[cb*3+0], k1 = cam_k[cb*3+1], k2 = cam_k[cb*3+2];
    float p0 = cam_p[cb*2+0], p1 = cam_p[cb*2+1];
    float cenx = center[cb*2+0], ceny = center[cb*2+1];
    float scx = scale[cb*2+0],  scy = scale[cb*2+1];

    float dx = gx - T[0], dy = gy - T[1], dz = gz - T[2];
    float xc = R[0]*dx + R[1]*dy + R[2]*dz;
    float yc = R[3]*dx + R[4]*dy + R[5]*dz;
    float zc = R[6]*dx + R[7]*dy + R[8]*dz;
    float invz = 1.0f / (zc + 1e-5f);
    float ux = xc * invz, uy = yc * invz;
    float r2 = ux*ux + uy*uy;
    float radial = 1.0f + k0*r2 + k1*(r2*r2) + k2*(r2*r2*r2);
    float tn = p0*uy + p1*ux;
    float m  = radial + 2.0f*tn;
    float xd = ux*m + p1*r2;
    float yd = uy*m + p0*r2;
    float pixx = fx*xd + ccx;
    float pixy = fy*yd + ccy;

    float whx = 2.0f*cenx, why = 2.0f*ceny;
    float bnd = (pixx >= 0.0f && pixy >= 0.0f && pixx < whx && pixy < why) ? 1.0f : 0.0f;
    float mwh = fmaxf(whx, why);
    pixx = fminf(fmaxf(pixx, -1.0f), mwh);
    pixy = fminf(fmaxf(pixy, -1.0f), mwh);

    float hsx = 200.0f*scx, hsy = 200.0f*scy;
    float xyx = (pixx * (960.0f/hsx) + 960.0f*(-cenx/hsx + 0.5f)) * 0.25f;
    float xyy = (pixy * (512.0f/hsy) + 512.0f*(-ceny/hsy + 0.5f)) * 0.25f;
    float sgx = (xyx / 239.0f) * 2.0f - 1.0f;
    float sgy = (xyy / 127.0f) * 2.0f - 1.0f;
    sgx = fminf(fmaxf(sgx, -1.1f), 1.1f);
    sgy = fminf(fmaxf(sgy, -1.1f), 1.1f);

    float pxf = (sgx + 1.0f) * 0.5f * 239.0f;
    float pyf = (sgy + 1.0f) * 0.5f * 127.0f;
    float x0f = floorf(pxf), y0f = floorf(pyf);
    float wx = pxf - x0f, wy = pyf - y0f;
    int x0 = (int)x0f, y0 = (int)y0f;
    int x1 = x0 + 1,   y1 = y0 + 1;
    float vx0 = (x0 >= 0 && x0 < WD) ? 1.0f : 0.0f;
    float vx1 = (x1 >= 0 && x1 < WD) ? 1.0f : 0.0f;
    float vy0 = (y0 >= 0 && y0 < HD) ? 1.0f : 0.0f;
    float vy1 = (y1 >= 0 && y1 < HD) ? 1.0f : 0.0f;

    ViewSample s;
    s.cx0 = min(max(x0, 0), WD-1);
    s.cx1 = min(max(x1, 0), WD-1);
    s.cy0 = min(max(y0, 0), HD-1);
    s.cy1 = min(max(y1, 0), HD-1);
    s.w[0] = (1.0f-wx)*(1.0f-wy) * vx0*vy0 * bnd;
    s.w[1] = wx*(1.0f-wy)        * vx1*vy0 * bnd;
    s.w[2] = (1.0f-wx)*wy        * vx0*vy1 * bnd;
    s.w[3] = wx*wy               * vx1*vy1 * bnd;
    s.bnd = bnd;
    return s;
}

__device__ __forceinline__ void grid_coords(int nn, float& gx, float& gy, float& gz) {
    int iz = nn % CZ;
    int iy = (nn / CZ) % CY;
    int ix = nn / (CZ*CY);
    // match np.linspace + SPACE_CENTER op order exactly (double, then f32 cast)
    gx = (float)(((double)ix * (8000.0/79.0) - 4000.0) + 0.0);
    gy = (float)(((double)iy * (8000.0/79.0) - 4000.0) - 500.0);
    gz = (float)(((double)iz * (2000.0/19.0) - 1000.0) + 800.0);
}

// ---------------------------------------------------------------------------
// Pre-pass: [v][b][j][y][x] f32 -> [v][b][y][x][j_pad16] f16 (32B per pixel)
// ---------------------------------------------------------------------------
__global__ __launch_bounds__(256) void hm_transpose_f16(
    const float* __restrict__ hm, __half* __restrict__ out)
{
    int idx = blockIdx.x * 256 + threadIdx.x;     // over NV*NB*HD*WD = 614400
    if (idx >= NV*NB*HD*WD) return;
    int x  = idx % WD;
    int y  = (idx / WD) % HD;
    int vb = idx / (WD*HD);
    const float* src = hm + ((size_t)vb*NJ*HD + (size_t)y)*WD + x;
    union { float4 f4[2]; __half h[16]; } u;
    #pragma unroll
    for (int j = 0; j < NJ; ++j) u.h[j] = __float2half(src[(size_t)j*HD*WD]);
    u.h[15] = __float2half(0.0f);
    float4* dst = reinterpret_cast<float4*>(out + (size_t)idx * JP16);  // 32B aligned
    dst[0] = u.f4[0];
    dst[1] = u.f4[1];
}

// ---------------------------------------------------------------------------
// Main kernel: branch-free fp16 gather, 32B per corner, XCD-swizzled blocks.
// ---------------------------------------------------------------------------
__global__ __launch_bounds__(256) void project_kernel_f16(
    const __half* __restrict__ hmT,
    const float* __restrict__ cam_R, const float* __restrict__ cam_T,
    const float* __restrict__ cam_f, const float* __restrict__ cam_c,
    const float* __restrict__ cam_k, const float* __restrict__ cam_p,
    const float* __restrict__ center, const float* __restrict__ scale,
    float* __restrict__ out_cubes, float* __restrict__ out_grids)
{
    // XCD swizzle: blocks round-robin XCDs by blockIdx%8; give XCD k a
    // contiguous chunk so each XCD works one batch b (L2 working set 4.9MB).
    int wg   = (int)blockIdx.x;
    int swz  = (wg % 8) * (NWG/8) + wg / 8;      // bijective, NWG%8==0
    const int b  = swz / BLOCKS_PER_B;           // wave-uniform
    const int nn = (swz % BLOCKS_PER_B)*256 + threadIdx.x;

    float gx, gy, gz;
    grid_coords(nn, gx, gy, gz);

    float wts[NV][4];
    int   offs[NV][4];
    float den = 0.0f;

    #pragma unroll
    for (int v = 0; v < NV; ++v) {
        int cb = v*NB + b;
        ViewSample s = project_one_view(gx, gy, gz, cam_R, cam_T, cam_f, cam_c,
                                        cam_k, cam_p, center, scale, cb);
        wts[v][0] = s.w[0]; wts[v][1] = s.w[1];
        wts[v][2] = s.w[2]; wts[v][3] = s.w[3];
        int base = cb * (HD*WD*JP16);
        offs[v][0] = base + (s.cy0*WD + s.cx0)*JP16;
        offs[v][1] = base + (s.cy0*WD + s.cx1)*JP16;
        offs[v][2] = base + (s.cy1*WD + s.cx0)*JP16;
        offs[v][3] = base + (s.cy1*WD + s.cx1)*JP16;
        den += s.bnd;
    }

    float acc[NJ];
    #pragma unroll
    for (int j = 0; j < NJ; ++j) acc[j] = 0.0f;

    #pragma unroll
    for (int v = 0; v < NV; ++v) {
        #pragma unroll
        for (int c = 0; c < 4; ++c) {
            float w = wts[v][c];
            union { float4 f4[2]; __half2 h2[8]; } u;
            const float4* p = reinterpret_cast<const float4*>(hmT + offs[v][c]);
            u.f4[0] = p[0];
            u.f4[1] = p[1];
            #pragma unroll
            for (int k = 0; k < 7; ++k) {
                float2 f = __half22float2(u.h2[k]);
                acc[2*k]   += w * f.x;
                acc[2*k+1] += w * f.y;
            }
            float2 f7 = __half22float2(u.h2[7]);
            acc[14] += w * f7.x;
        }
    }

    float inv_den = 1.0f / (den + 1e-6f);
    #pragma unroll
    for (int j = 0; j < NJ; ++j) {
        float val = fminf(fmaxf(acc[j]*inv_den, 0.0f), 1.0f);
        out_cubes[((size_t)b*NJ + j)*NPTS + nn] = val;       // coalesced
    }
    float* g = out_grids + ((size_t)b*NPTS + nn)*3;
    g[0] = gx; g[1] = gy; g[2] = gz;
}

// ---------------------------------------------------------------------------
// Fallback: direct gather from the native layout (if ws too small).
// ---------------------------------------------------------------------------
__global__ __launch_bounds__(256) void project_kernel_direct(
    const float* __restrict__ hm,
    const float* __restrict__ cam_R, const float* __restrict__ cam_T,
    const float* __restrict__ cam_f, const float* __restrict__ cam_c,
    const float* __restrict__ cam_k, const float* __restrict__ cam_p,
    const float* __restrict__ center, const float* __restrict__ scale,
    float* __restrict__ out_cubes, float* __restrict__ out_grids)
{
    const int b  = blockIdx.x / BLOCKS_PER_B;
    const int nn = (blockIdx.x % BLOCKS_PER_B)*256 + threadIdx.x;

    float gx, gy, gz;
    grid_coords(nn, gx, gy, gz);

    float wts[NV][4];
    int   offs[NV][4];
    float den = 0.0f;

    #pragma unroll
    for (int v = 0; v < NV; ++v) {
        int cb = v*NB + b;
        ViewSample s = project_one_view(gx, gy, gz, cam_R, cam_T, cam_f, cam_c,
                                        cam_k, cam_p, center, scale, cb);
        wts[v][0] = s.w[0]; wts[v][1] = s.w[1];
        wts[v][2] = s.w[2]; wts[v][3] = s.w[3];
        offs[v][0] = s.cy0*WD + s.cx0;
        offs[v][1] = s.cy0*WD + s.cx1;
        offs[v][2] = s.cy1*WD + s.cx0;
        offs[v][3] = s.cy1*WD + s.cx1;
        den += s.bnd;
    }

    float acc[NJ];
    #pragma unroll
    for (int j = 0; j < NJ; ++j) acc[j] = 0.0f;

    #pragma unroll
    for (int v = 0; v < NV; ++v) {
        int cb = v*NB + b;
        #pragma unroll
        for (int j = 0; j < NJ; ++j) {
            const float* base = hm + ((size_t)cb*NJ + j)*(HD*WD);
            acc[j] += wts[v][0]*base[offs[v][0]] + wts[v][1]*base[offs[v][1]]
                    + wts[v][2]*base[offs[v][2]] + wts[v][3]*base[offs[v][3]];
        }
    }

    float inv_den = 1.0f / (den + 1e-6f);
    #pragma unroll
    for (int j = 0; j < NJ; ++j) {
        float val = fminf(fmaxf(acc[j]*inv_den, 0.0f), 1.0f);
        out_cubes[((size_t)b*NJ + j)*NPTS + nn] = val;
    }
    float* g = out_grids + ((size_t)b*NPTS + nn)*3;
    g[0] = gx; g[1] = gy; g[2] = gz;
}

// ---------------------------------------------------------------------------
extern "C" void kernel_launch(void* const* d_in, const int* in_sizes, int n_in,
                              void* d_out, int out_size, void* d_ws, size_t ws_size,
                              hipStream_t stream) {
    const float* hm     = (const float*)d_in[0];
    const float* cam_R  = (const float*)d_in[1];
    const float* cam_T  = (const float*)d_in[2];
    const float* cam_f  = (const float*)d_in[3];
    const float* cam_c  = (const float*)d_in[4];
    const float* cam_k  = (const float*)d_in[5];
    const float* cam_p  = (const float*)d_in[6];
    const float* center = (const float*)d_in[7];
    const float* scale  = (const float*)d_in[8];

    float* out_cubes = (float*)d_out;
    float* out_grids = out_cubes + (size_t)NB*NJ*NPTS;

    size_t need = (size_t)NV*NB*HD*WD*JP16*sizeof(__half);   // 19.66 MB
    if (ws_size >= need) {
        __half* hmT = (__half*)d_ws;
        hipLaunchKernelGGL(hm_transpose_f16,
                           dim3((NV*NB*HD*WD)/256), dim3(256), 0, stream, hm, hmT);
        hipLaunchKernelGGL(project_kernel_f16,
                           dim3(NWG), dim3(256), 0, stream,
                           hmT, cam_R, cam_T, cam_f, cam_c, cam_k, cam_p,
                           center, scale, out_cubes, out_grids);
    } else {
        hipLaunchKernelGGL(project_kernel_direct,
                           dim3(NWG), dim3(256), 0, stream,
                           hm, cam_R, cam_T, cam_f, cam_c, cam_k, cam_p,
                           center, scale, out_cubes, out_grids);
    }
}

// Round 4
// 125.791 us; speedup vs baseline: 1.0772x; 1.0075x over previous
//
#include <hip/hip_runtime.h>
#include <hip/hip_fp16.h>

#define NV 5
#define NB 4
#define NJ 15
#define HD 128
#define WD 240
#define CX 80
#define CY 80
#define CZ 20
#define NPTS (CX*CY*CZ)   /* 128000 */
#define JP16 16           /* padded joint dim in halves: 32B per pixel */
#define BLOCKS_PER_B (NPTS/256)   /* 500 */
#define NWG (NB*BLOCKS_PER_B)     /* 2000, divisible by 8 XCDs */

// ---------------------------------------------------------------------------
struct ViewSample {
    float w[4];     // w00, w10, w01, w11 (validity + bounding folded in)
    int   cx0, cx1, cy0, cy1;
    float bnd;
};

__device__ __forceinline__ ViewSample project_one_view(
    float gx, float gy, float gz,
    const float* __restrict__ cam_R, const float* __restrict__ cam_T,
    const float* __restrict__ cam_f, const float* __restrict__ cam_c,
    const float* __restrict__ cam_k, const float* __restrict__ cam_p,
    const float* __restrict__ center, const float* __restrict__ scale,
    int cb)
{
    const float* R = cam_R + cb*9;
    const float* T = cam_T + cb*3;
    float fx = cam_f[cb*2+0], fy = cam_f[cb*2+1];
    float ccx = cam_c[cb*2+0], ccy = cam_c[cb*2+1];
    float k0 = cam_k[cb*3+0], k1 = cam_k[cb*3+1], k2 = cam_k[cb*3+2];
    float p0 = cam_p[cb*2+0], p1 = cam_p[cb*2+1];
    float cenx = center[cb*2+0], ceny = center[cb*2+1];
    float scx = scale[cb*2+0],  scy = scale[cb*2+1];

    float dx = gx - T[0], dy = gy - T[1], dz = gz - T[2];
    float xc = R[0]*dx + R[1]*dy + R[2]*dz;
    float yc = R[3]*dx + R[4]*dy + R[5]*dz;
    float zc = R[6]*dx + R[7]*dy + R[8]*dz;
    float invz = 1.0f / (zc + 1e-5f);
    float ux = xc * invz, uy = yc * invz;
    float r2 = ux*ux + uy*uy;
    float radial = 1.0f + k0*r2 + k1*(r2*r2) + k2*(r2*r2*r2);
    float tn = p0*uy + p1*ux;
    float m  = radial + 2.0f*tn;
    float xd = ux*m + p1*r2;
    float yd = uy*m + p0*r2;
    float pixx = fx*xd + ccx;
    float pixy = fy*yd + ccy;

    float whx = 2.0f*cenx, why = 2.0f*ceny;
    float bnd = (pixx >= 0.0f && pixy >= 0.0f && pixx < whx && pixy < why) ? 1.0f : 0.0f;
    float mwh = fmaxf(whx, why);
    pixx = fminf(fmaxf(pixx, -1.0f), mwh);
    pixy = fminf(fmaxf(pixy, -1.0f), mwh);

    float hsx = 200.0f*scx, hsy = 200.0f*scy;
    float xyx = (pixx * (960.0f/hsx) + 960.0f*(-cenx/hsx + 0.5f)) * 0.25f;
    float xyy = (pixy * (512.0f/hsy) + 512.0f*(-ceny/hsy + 0.5f)) * 0.25f;
    float sgx = (xyx / 239.0f) * 2.0f - 1.0f;
    float sgy = (xyy / 127.0f) * 2.0f - 1.0f;
    sgx = fminf(fmaxf(sgx, -1.1f), 1.1f);
    sgy = fminf(fmaxf(sgy, -1.1f), 1.1f);

    float pxf = (sgx + 1.0f) * 0.5f * 239.0f;
    float pyf = (sgy + 1.0f) * 0.5f * 127.0f;
    float x0f = floorf(pxf), y0f = floorf(pyf);
    float wx = pxf - x0f, wy = pyf - y0f;
    int x0 = (int)x0f, y0 = (int)y0f;
    int x1 = x0 + 1,   y1 = y0 + 1;
    float vx0 = (x0 >= 0 && x0 < WD) ? 1.0f : 0.0f;
    float vx1 = (x1 >= 0 && x1 < WD) ? 1.0f : 0.0f;
    float vy0 = (y0 >= 0 && y0 < HD) ? 1.0f : 0.0f;
    float vy1 = (y1 >= 0 && y1 < HD) ? 1.0f : 0.0f;

    ViewSample s;
    s.cx0 = min(max(x0, 0), WD-1);
    s.cx1 = min(max(x1, 0), WD-1);
    s.cy0 = min(max(y0, 0), HD-1);
    s.cy1 = min(max(y1, 0), HD-1);
    s.w[0] = (1.0f-wx)*(1.0f-wy) * vx0*vy0 * bnd;
    s.w[1] = wx*(1.0f-wy)        * vx1*vy0 * bnd;
    s.w[2] = (1.0f-wx)*wy        * vx0*vy1 * bnd;
    s.w[3] = wx*wy               * vx1*vy1 * bnd;
    s.bnd = bnd;
    return s;
}

__device__ __forceinline__ void grid_coords(int nn, float& gx, float& gy, float& gz) {
    int iz = nn % CZ;
    int iy = (nn / CZ) % CY;
    int ix = nn / (CZ*CY);
    gx = (float)(((double)ix * (8000.0/79.0) - 4000.0) + 0.0);
    gy = (float)(((double)iy * (8000.0/79.0) - 4000.0) - 500.0);
    gz = (float)(((double)iz * (2000.0/19.0) - 1000.0) + 800.0);
}

// ---------------------------------------------------------------------------
// Pre-pass: [v][b][j][y][x] f32 -> [v][b][y][x][j_pad16] f16 (32B per pixel)
// ---------------------------------------------------------------------------
__global__ __launch_bounds__(256) void hm_transpose_f16(
    const float* __restrict__ hm, __half* __restrict__ out)
{
    int idx = blockIdx.x * 256 + threadIdx.x;     // over NV*NB*HD*WD = 614400
    if (idx >= NV*NB*HD*WD) return;
    int x  = idx % WD;
    int y  = (idx / WD) % HD;
    int vb = idx / (WD*HD);
    const float* src = hm + ((size_t)vb*NJ*HD + (size_t)y)*WD + x;
    union { float4 f4[2]; __half h[16]; } u;
    #pragma unroll
    for (int j = 0; j < NJ; ++j) u.h[j] = __float2half(src[(size_t)j*HD*WD]);
    u.h[15] = __float2half(0.0f);
    float4* dst = reinterpret_cast<float4*>(out + (size_t)idx * JP16);  // 32B aligned
    dst[0] = u.f4[0];
    dst[1] = u.f4[1];
}

// ---------------------------------------------------------------------------
// Main kernel: fp16 gather with wave-level view skip + per-lane predication.
// ---------------------------------------------------------------------------
__global__ __launch_bounds__(256) void project_kernel_f16(
    const __half* __restrict__ hmT,
    const float* __restrict__ cam_R, const float* __restrict__ cam_T,
    const float* __restrict__ cam_f, const float* __restrict__ cam_c,
    const float* __restrict__ cam_k, const float* __restrict__ cam_p,
    const float* __restrict__ center, const float* __restrict__ scale,
    float* __restrict__ out_cubes, float* __restrict__ out_grids)
{
    int wg   = (int)blockIdx.x;
    int swz  = (wg % 8) * (NWG/8) + wg / 8;      // bijective XCD swizzle
    const int b  = swz / BLOCKS_PER_B;           // wave-uniform
    const int nn = (swz % BLOCKS_PER_B)*256 + threadIdx.x;

    float gx, gy, gz;
    grid_coords(nn, gx, gy, gz);

    float wts[NV][4];
    int   offs[NV][4];
    float den = 0.0f;

    #pragma unroll
    for (int v = 0; v < NV; ++v) {
        int cb = v*NB + b;
        ViewSample s = project_one_view(gx, gy, gz, cam_R, cam_T, cam_f, cam_c,
                                        cam_k, cam_p, center, scale, cb);
        wts[v][0] = s.w[0]; wts[v][1] = s.w[1];
        wts[v][2] = s.w[2]; wts[v][3] = s.w[3];
        int base = cb * (HD*WD*JP16);
        offs[v][0] = base + (s.cy0*WD + s.cx0)*JP16;
        offs[v][1] = base + (s.cy0*WD + s.cx1)*JP16;
        offs[v][2] = base + (s.cy1*WD + s.cx0)*JP16;
        offs[v][3] = base + (s.cy1*WD + s.cx1)*JP16;
        den += s.bnd;
    }

    float acc[NJ];
    #pragma unroll
    for (int j = 0; j < NJ; ++j) acc[j] = 0.0f;

    #pragma unroll
    for (int v = 0; v < NV; ++v) {
        float wsum = wts[v][0] + wts[v][1] + wts[v][2] + wts[v][3];
        // Wave-level skip: most (wave,view) pairs are fully out-of-frustum.
        if (__any(wsum > 0.0f)) {
            #pragma unroll
            for (int c = 0; c < 4; ++c) {
                float w = wts[v][c];
                // Per-lane predication: masked lanes issue no L1 transactions.
                if (w != 0.0f) {
                    union { float4 f4[2]; __half2 h2[8]; } u;
                    const float4* p = reinterpret_cast<const float4*>(hmT + offs[v][c]);
                    u.f4[0] = p[0];
                    u.f4[1] = p[1];
                    #pragma unroll
                    for (int k = 0; k < 7; ++k) {
                        float2 f = __half22float2(u.h2[k]);
                        acc[2*k]   += w * f.x;
                        acc[2*k+1] += w * f.y;
                    }
                    float2 f7 = __half22float2(u.h2[7]);
                    acc[14] += w * f7.x;
                }
            }
        }
    }

    float inv_den = 1.0f / (den + 1e-6f);
    #pragma unroll
    for (int j = 0; j < NJ; ++j) {
        float val = fminf(fmaxf(acc[j]*inv_den, 0.0f), 1.0f);
        out_cubes[((size_t)b*NJ + j)*NPTS + nn] = val;       // coalesced
    }
    float* g = out_grids + ((size_t)b*NPTS + nn)*3;
    g[0] = gx; g[1] = gy; g[2] = gz;
}

// ---------------------------------------------------------------------------
// Fallback: direct gather from the native layout (if ws too small).
// ---------------------------------------------------------------------------
__global__ __launch_bounds__(256) void project_kernel_direct(
    const float* __restrict__ hm,
    const float* __restrict__ cam_R, const float* __restrict__ cam_T,
    const float* __restrict__ cam_f, const float* __restrict__ cam_c,
    const float* __restrict__ cam_k, const float* __restrict__ cam_p,
    const float* __restrict__ center, const float* __restrict__ scale,
    float* __restrict__ out_cubes, float* __restrict__ out_grids)
{
    const int b  = blockIdx.x / BLOCKS_PER_B;
    const int nn = (blockIdx.x % BLOCKS_PER_B)*256 + threadIdx.x;

    float gx, gy, gz;
    grid_coords(nn, gx, gy, gz);

    float wts[NV][4];
    int   offs[NV][4];
    float den = 0.0f;

    #pragma unroll
    for (int v = 0; v < NV; ++v) {
        int cb = v*NB + b;
        ViewSample s = project_one_view(gx, gy, gz, cam_R, cam_T, cam_f, cam_c,
                                        cam_k, cam_p, center, scale, cb);
        wts[v][0] = s.w[0]; wts[v][1] = s.w[1];
        wts[v][2] = s.w[2]; wts[v][3] = s.w[3];
        offs[v][0] = s.cy0*WD + s.cx0;
        offs[v][1] = s.cy0*WD + s.cx1;
        offs[v][2] = s.cy1*WD + s.cx0;
        offs[v][3] = s.cy1*WD + s.cx1;
        den += s.bnd;
    }

    float acc[NJ];
    #pragma unroll
    for (int j = 0; j < NJ; ++j) acc[j] = 0.0f;

    #pragma unroll
    for (int v = 0; v < NV; ++v) {
        float wsum = wts[v][0] + wts[v][1] + wts[v][2] + wts[v][3];
        if (__any(wsum > 0.0f)) {
            int cb = v*NB + b;
            #pragma unroll
            for (int j = 0; j < NJ; ++j) {
                const float* base = hm + ((size_t)cb*NJ + j)*(HD*WD);
                acc[j] += wts[v][0]*base[offs[v][0]] + wts[v][1]*base[offs[v][1]]
                        + wts[v][2]*base[offs[v][2]] + wts[v][3]*base[offs[v][3]];
            }
        }
    }

    float inv_den = 1.0f / (den + 1e-6f);
    #pragma unroll
    for (int j = 0; j < NJ; ++j) {
        float val = fminf(fmaxf(acc[j]*inv_den, 0.0f), 1.0f);
        out_cubes[((size_t)b*NJ + j)*NPTS + nn] = val;
    }
    float* g = out_grids + ((size_t)b*NPTS + nn)*3;
    g[0] = gx; g[1] = gy; g[2] = gz;
}

// ---------------------------------------------------------------------------
extern "C" void kernel_launch(void* const* d_in, const int* in_sizes, int n_in,
                              void* d_out, int out_size, void* d_ws, size_t ws_size,
                              hipStream_t stream) {
    const float* hm     = (const float*)d_in[0];
    const float* cam_R  = (const float*)d_in[1];
    const float* cam_T  = (const float*)d_in[2];
    const float* cam_f  = (const float*)d_in[3];
    const float* cam_c  = (const float*)d_in[4];
    const float* cam_k  = (const float*)d_in[5];
    const float* cam_p  = (const float*)d_in[6];
    const float* center = (const float*)d_in[7];
    const float* scale  = (const float*)d_in[8];

    float* out_cubes = (float*)d_out;
    float* out_grids = out_cubes + (size_t)NB*NJ*NPTS;

    size_t need = (size_t)NV*NB*HD*WD*JP16*sizeof(__half);   // 19.66 MB
    if (ws_size >= need) {
        __half* hmT = (__half*)d_ws;
        hipLaunchKernelGGL(hm_transpose_f16,
                           dim3((NV*NB*HD*WD)/256), dim3(256), 0, stream, hm, hmT);
        hipLaunchKernelGGL(project_kernel_f16,
                           dim3(NWG), dim3(256), 0, stream,
                           hmT, cam_R, cam_T, cam_f, cam_c, cam_k, cam_p,
                           center, scale, out_cubes, out_grids);
    } else {
        hipLaunchKernelGGL(project_kernel_direct,
                           dim3(NWG), dim3(256), 0, stream,
                           hm, cam_R, cam_T, cam_f, cam_c, cam_k, cam_p,
                           center, scale, out_cubes, out_grids);
    }
}